// Round 6
// baseline (539.623 us; speedup 1.0000x reference)
//
#include <hip/hip_runtime.h>

typedef unsigned short UST;
typedef unsigned char U8;
typedef __bf16 bf16x8 __attribute__((ext_vector_type(8)));
typedef float floatx4 __attribute__((ext_vector_type(4)));
typedef unsigned short ushort8v __attribute__((ext_vector_type(8)));
typedef unsigned short ushort4v __attribute__((ext_vector_type(4)));

#define N_NODES 20000
#define E_EDGES 320000
#define KE 928         // padded edge-MLP K: [hi 0:256 | hj 256:512 | fd(interleaved sin/cos) 512:896 | le 896:905 | pad:928]
#define M_PAD 20096    // 157*128

static __device__ __forceinline__ UST f2bf(float x){
  unsigned int u = __float_as_uint(x);
  u += 0x7fffu + ((u >> 16) & 1u);   // round-to-nearest-even
  return (UST)(u >> 16);
}
static __device__ __forceinline__ float bf2f(UST u){
  return __uint_as_float(((unsigned int)u) << 16);
}
static __device__ __forceinline__ float siluf(float v){
  return v / (1.0f + __expf(-v));
}
static __device__ __forceinline__ U8 f2fp8(float v){
  // OCP e4m3 via HW pack (low byte of packed word)
  int p = __builtin_amdgcn_cvt_pk_fp8_f32(v, v, 0, false);
  return (U8)p;
}
// async global->LDS, 16B per lane; LDS dest must be wave-uniform base + lane*16
static __device__ __forceinline__ void gll16(const void* g, void* lds){
  __builtin_amdgcn_global_load_lds(
      (const __attribute__((address_space(1))) unsigned int*)g,
      (__attribute__((address_space(3))) unsigned int*)lds, 16, 0, 0);
}

// As: 128 rows x 32 cols (64B stride). Bs: 256 rows x 32 cols. Wave: 64x64 at (wM,wN).
static __device__ __forceinline__ void mfma_step(const UST* As, const UST* Bs,
    floatx4 (&acc)[4][4], int lm, int quad, int wM, int wN){
  bf16x8 a[4], b[4];
#pragma unroll
  for (int i = 0; i < 4; ++i)
    a[i] = *(const bf16x8*)(As + (wM + i*16 + lm)*32 + quad*8);
#pragma unroll
  for (int i = 0; i < 4; ++i)
    b[i] = *(const bf16x8*)(Bs + (wN + i*16 + lm)*32 + quad*8);
#pragma unroll
  for (int mi = 0; mi < 4; ++mi)
#pragma unroll
    for (int ni = 0; ni < 4; ++ni)
      acc[mi][ni] = __builtin_amdgcn_mfma_f32_16x16x32_bf16(a[mi], b[ni], acc[mi][ni], 0, 0, 0);
}

// fp8 variant: As 128x64B, Bs 256x64B dense; sub s selects 32-k half
static __device__ __forceinline__ void mfma_step_f8(const U8* As, const U8* Bs,
    floatx4 (&acc)[4][4], int lm, int quad, int wM, int wN, int s){
  long a[4], b[4];
#pragma unroll
  for (int i = 0; i < 4; ++i)
    a[i] = *(const long*)(As + (wM + i*16 + lm)*64 + s*32 + quad*8);
#pragma unroll
  for (int i = 0; i < 4; ++i)
    b[i] = *(const long*)(Bs + (wN + i*16 + lm)*64 + s*32 + quad*8);
#pragma unroll
  for (int mi = 0; mi < 4; ++mi)
#pragma unroll
    for (int ni = 0; ni < 4; ++ni)
      acc[mi][ni] = __builtin_amdgcn_mfma_f32_16x16x32_fp8_fp8(a[mi], b[ni], acc[mi][ni], 0, 0, 0);
}

// ---------------- fused prep: W1T/W2f8/Wn1T/Wn2T + LayerNorm + ltl ----------------
// W1T row map: [0:512)=hi|hj, [512:896)=fd interleaved (col 512+2j+b -> orig 521+b*192+j),
// [896:905)=le (orig 512..520), [905:928)=0
__global__ __launch_bounds__(256) void prep_all(
    const float* __restrict__ We1, const float* __restrict__ We2,
    const float* __restrict__ Wn1, const float* __restrict__ Wn2,
    const float* __restrict__ x, const float* __restrict__ gamma,
    const float* __restrict__ beta, const float* __restrict__ lat,
    UST* __restrict__ W1T, U8* __restrict__ W2f8,
    UST* __restrict__ Wn1T, UST* __restrict__ Wn2T,
    UST* __restrict__ h, float* __restrict__ ltl){
  int bid = blockIdx.x, t = threadIdx.x;
  if (bid < 928){                                   // W1T
    int i = bid*256 + t;
    int n = i / KE, k = i % KE;
    float v = 0.0f;
    if (k < 512)      v = We1[(size_t)k*256 + n];
    else if (k < 896){
      int idx = k - 512, j = idx >> 1, b = idx & 1;
      v = We1[(size_t)(521 + b*192 + j)*256 + n];
    }
    else if (k < 905) v = We1[(size_t)(k-384)*256 + n];
    W1T[i] = f2bf(v);
  } else if (bid < 1184){                           // W2 (fp8 x16) + Wn2T
    int i = (bid-928)*256 + t;
    int n = i >> 8, k = i & 255;
    Wn2T[i] = f2bf(Wn2[(size_t)k*256 + n]);
    W2f8[i] = f2fp8(We2[(size_t)k*256 + n] * 16.0f);
  } else if (bid < 1696){                           // Wn1T
    int i = (bid-1184)*256 + t;
    int n = i >> 9, k = i & 511;
    Wn1T[i] = f2bf(Wn1[(size_t)k*256 + n]);
  } else if (bid < 6696){                           // LayerNorm, 4 rows/block
    int wave = t >> 6, lane = t & 63;
    int row = (bid-1696)*4 + wave;
    const float4* xp = (const float4*)(x + (size_t)row * 256);
    float4 v = xp[lane];
    float s  = v.x + v.y + v.z + v.w;
    float sq = v.x*v.x + v.y*v.y + v.z*v.z + v.w*v.w;
#pragma unroll
    for (int o = 32; o > 0; o >>= 1){ s += __shfl_xor(s, o); sq += __shfl_xor(sq, o); }
    float mu  = s * (1.0f/256.0f);
    float var = sq * (1.0f/256.0f) - mu*mu;
    float rs  = rsqrtf(var + 1e-5f);
    float4 g = ((const float4*)gamma)[lane];
    float4 b = ((const float4*)beta)[lane];
    ushort4v o4;
    o4[0] = f2bf((v.x-mu)*rs*g.x + b.x);
    o4[1] = f2bf((v.y-mu)*rs*g.y + b.y);
    o4[2] = f2bf((v.z-mu)*rs*g.z + b.z);
    o4[3] = f2bf((v.w-mu)*rs*g.w + b.w);
    *(ushort4v*)(h + (size_t)row*256 + lane*4) = o4;
  } else {                                          // ltl = L @ L^T
    int i = (bid-6696)*256 + t;
    if (i < 9000){
      int g = i / 9, ij = i % 9, a = ij / 3, b = ij % 3;
      const float* L = lat + g*9;
      ltl[i] = L[a*3+0]*L[b*3+0] + L[a*3+1]*L[b*3+1] + L[a*3+2]*L[b*3+2];
    }
  }
}

// ---------------- CSR build: histogram -> scan -> fill (+sorted srcs) ----------------
__global__ __launch_bounds__(256) void cnt_kernel(const int* __restrict__ src,
                                                  int* __restrict__ cnti){
  int e = blockIdx.x*256 + threadIdx.x;
  if (e < E_EDGES) atomicAdd(&cnti[src[e]], 1);
}

__global__ __launch_bounds__(256) void scan_kernel(const int* __restrict__ cnti,
    int* __restrict__ off, int* __restrict__ head){
  __shared__ int ps[256];
  int t = threadIdx.x;
  const int CH = 80;                       // 256*80 = 20480 >= 20000 (cnti padded)
  const int4* cp = (const int4*)cnti;
  int base = t * CH;
  int s = 0;
#pragma unroll 1
  for (int i = 0; i < CH/4; ++i){
    int4 v = cp[t*(CH/4) + i];
    int idx = base + i*4;
    if (idx   < N_NODES) s += v.x;
    if (idx+1 < N_NODES) s += v.y;
    if (idx+2 < N_NODES) s += v.z;
    if (idx+3 < N_NODES) s += v.w;
  }
  ps[t] = s; __syncthreads();
#pragma unroll 1
  for (int o = 1; o < 256; o <<= 1){
    int v = (t >= o) ? ps[t - o] : 0;
    __syncthreads();
    ps[t] += v;
    __syncthreads();
  }
  int run = (t > 0) ? ps[t-1] : 0;
#pragma unroll 1
  for (int i = 0; i < CH/4; ++i){
    int4 v = cp[t*(CH/4) + i];
    int idx = base + i*4;
    int a4[4] = {v.x, v.y, v.z, v.w};
#pragma unroll
    for (int j = 0; j < 4; ++j){
      int id = idx + j;
      if (id < N_NODES){ off[id] = run; head[id] = run; run += a4[j]; }
    }
  }
  if (t == 255) off[N_NODES] = run;
}

__global__ __launch_bounds__(256) void fill_kernel(const int* __restrict__ src,
    int* __restrict__ head, int* __restrict__ eidx, int* __restrict__ srcs){
  int e = blockIdx.x*256 + threadIdx.x;
  if (e < E_EDGES){
    int s = src[e];
    int p = atomicAdd(&head[s], 1);
    eidx[p] = e;
    srcs[p] = s;
  }
}

// ======== MEGA-KERNEL: edge MLP1 + MLP2(fp8) + segmented scatter ========
// Phase 1 (bf16): e1 = silu(x @ We1 + be1) -> fp8 e4m3 tile in global scratch.
// Phase 2 (fp8):  e2pre = (e1f8 @ W2f8)/16 + be2 (L2-hot readback of own tile).
// Phase 3: silu -> EsT col-major LDS -> 2-half segmented col sums -> atomicAdd sums.
__global__ __launch_bounds__(512)
void gemm_edge_fused(const UST* __restrict__ h, const int* __restrict__ ei,
                     const int* __restrict__ e2g, const float* __restrict__ fdif,
                     const float* __restrict__ ltl, const UST* __restrict__ W1T,
                     const float* __restrict__ be1, const int* __restrict__ eidx,
                     const U8* __restrict__ W2f8, const float* __restrict__ be2,
                     const int* __restrict__ rownode,
                     U8* __restrict__ e1f8, float* __restrict__ sums){
  __shared__ __attribute__((aligned(16))) UST lds[256*132];  // 67.6KB union
  __shared__ int rn[128];
  UST* As0 = lds;             // ph1: 128*32 bf16
  UST* As1 = lds + 4096;
  UST* Bs0 = lds + 8192;      // ph1: 256*32 bf16
  UST* Bs1 = lds + 16384;
  U8*  As8 = (U8*)lds;        // ph2: 128*64 fp8 (8KB)
  U8*  Bs8 = (U8*)lds + 8192; // ph2: 256*64 fp8 (16KB)
  UST* EsT = lds;             // ph3: [256 cols][132 rows pad]
  int t = threadIdx.x;
  int bM = blockIdx.x;
  int rA = t >> 2, cA = (t & 3) * 8;       // one A-row per thread, 8-ushort chunk
  int p0 = bM*128 + rA;
  int e0 = eidx[p0];
  int src0 = ei[e0];
  int dst0 = ei[E_EDGES + e0];
  int g0 = e2g[e0];
  float f0x = fdif[e0*3+0], f0y = fdif[e0*3+1], f0z = fdif[e0*3+2];
  size_t btb0 = (size_t)rA*KE + cA;        // W1T rows rA, rA+128
  size_t btb1 = btb0 + (size_t)128*KE;
  int lane = t & 63, lm = lane & 15, quad = lane >> 4;
  int wave = t >> 6, wM = (wave >> 2)*64, wN = (wave & 3)*64;
  floatx4 acc[4][4] = {};
  UST* a0d = &As0[rA*32 + cA];
  UST* a1d = &As1[rA*32 + cA];
  UST* b0d0 = &Bs0[rA*32 + cA];
  UST* b0d1 = &Bs0[(128+rA)*32 + cA];
  UST* b1d0 = &Bs1[rA*32 + cA];
  UST* b1d1 = &Bs1[(128+rA)*32 + cA];
  if (t < 128) rn[t] = rownode[bM*128 + t];

  // ---- phase 1: K-loop over KE ----
#pragma unroll 1
  for (int w = 0; w < 8; ++w){            // hi (w<4) then hj (w>=4)
    int k0 = w*64;
    const UST* srow = (w < 4) ? (h + (size_t)src0*256 + k0)
                              : (h + (size_t)dst0*256 + (k0 - 256));
    gll16(srow + cA,      a0d);
    gll16(srow + 32 + cA, a1d);
    gll16(W1T + btb0 + k0,      b0d0);
    gll16(W1T + btb1 + k0,      b0d1);
    gll16(W1T + btb0 + k0 + 32, b1d0);
    gll16(W1T + btb1 + k0 + 32, b1d1);
    __syncthreads();
    mfma_step(As0, Bs0, acc, lm, quad, wM, wN);
    mfma_step(As1, Bs1, acc, lm, quad, wM, wN);
    __syncthreads();
  }
#pragma unroll 1
  for (int w = 8; w < 14; ++w){           // fd: interleaved sin/cos pairs
    int k0 = w*64;
    gll16(W1T + btb0 + k0,      b0d0);    // issue DMA before the VALU burst
    gll16(W1T + btb1 + k0,      b0d1);
    gll16(W1T + btb0 + k0 + 32, b1d0);
    gll16(W1T + btb1 + k0 + 32, b1d1);
    int jb0 = (k0 + cA - 512) >> 1;       // 4 angles per half-window
    ushort8v o0, o1;
#pragma unroll
    for (int ii = 0; ii < 4; ++ii){
      int jj = jb0 + ii;
      int dim = jj >> 6; float kf = (float)(jj & 63);
      float fr = (dim == 0) ? f0x : ((dim == 1) ? f0y : f0z);
      float q = __builtin_amdgcn_fractf(fr * kf);
      o0[2*ii]   = f2bf(__builtin_amdgcn_sinf(q));
      o0[2*ii+1] = f2bf(__builtin_amdgcn_cosf(q));
    }
#pragma unroll
    for (int ii = 0; ii < 4; ++ii){
      int jj = jb0 + 16 + ii;
      int dim = jj >> 6; float kf = (float)(jj & 63);
      float fr = (dim == 0) ? f0x : ((dim == 1) ? f0y : f0z);
      float q = __builtin_amdgcn_fractf(fr * kf);
      o1[2*ii]   = f2bf(__builtin_amdgcn_sinf(q));
      o1[2*ii+1] = f2bf(__builtin_amdgcn_cosf(q));
    }
    *(ushort8v*)a0d = o0;
    *(ushort8v*)a1d = o1;
    __syncthreads();
    mfma_step(As0, Bs0, acc, lm, quad, wM, wN);
    mfma_step(As1, Bs1, acc, lm, quad, wM, wN);
    __syncthreads();
  }
  {                                       // half window k0=896: le + pad (As0/Bs0 only)
    gll16(W1T + btb0 + 896, b0d0);
    gll16(W1T + btb1 + 896, b0d1);
    ushort8v o0;
#pragma unroll
    for (int i = 0; i < 8; ++i){
      int c = cA + i;
      o0[i] = (c < 9) ? f2bf(ltl[g0*9 + c]) : (UST)0;
    }
    *(ushort8v*)a0d = o0;
    __syncthreads();
    mfma_step(As0, Bs0, acc, lm, quad, wM, wN);
  }
  // phase-1 epilogue: silu -> fp8 tile (this block's rows only)
  {
    int mbase = bM*128 + wM + quad*4;
    int nbase = wN + lm;
#pragma unroll
    for (int mi = 0; mi < 4; ++mi)
#pragma unroll
      for (int r = 0; r < 4; ++r){
        int m = mbase + mi*16 + r;
#pragma unroll
        for (int ni = 0; ni < 4; ++ni){
          int n = nbase + ni*16;
          float v = acc[mi][ni][r] + be1[n];
          e1f8[(size_t)m*256 + n] = f2fp8(siluf(v));
        }
      }
  }
  __syncthreads();   // drains vmcnt(0): e1f8 tile visible; LDS buffers free

  // ---- phase 2: fp8 GEMM, K=256 (2x less staging than bf16) ----
  floatx4 acc2[4][4] = {};
  int rAf = t >> 2, cAf = (t & 3) * 16;
  const U8* e1b = e1f8 + (size_t)(bM*128 + rAf)*256 + cAf;
  U8* a8d  = As8 + rAf*64 + cAf;
  U8* b8d0 = Bs8 + rAf*64 + cAf;
  U8* b8d1 = Bs8 + (128+rAf)*64 + cAf;
#pragma unroll 1
  for (int k0 = 0; k0 < 256; k0 += 64){
    gll16(e1b + k0, a8d);
    gll16(W2f8 + (size_t)rAf*256 + k0 + cAf,       b8d0);
    gll16(W2f8 + (size_t)(128+rAf)*256 + k0 + cAf, b8d1);
    __syncthreads();
    mfma_step_f8(As8, Bs8, acc2, lm, quad, wM, wN, 0);
    mfma_step_f8(As8, Bs8, acc2, lm, quad, wM, wN, 1);
    __syncthreads();
  }
  // ---- phase 3: silu + transpose-store to EsT, 2-half segmented col sums ----
#pragma unroll
  for (int mi = 0; mi < 4; ++mi)
#pragma unroll
    for (int ni = 0; ni < 4; ++ni){
      int nl = wN + ni*16 + lm;
      int ml = wM + mi*16 + quad*4;
      ushort4v pk;
#pragma unroll
      for (int r = 0; r < 4; ++r)
        pk[r] = f2bf(siluf(acc2[mi][ni][r] * 0.0625f + be2[nl]));
      *(ushort4v*)&EsT[nl*132 + ml] = pk;
    }
  __syncthreads();
  {
    int c = t & 255, hh = t >> 8;        // all 512 threads: (col, row-half)
    int rbeg = hh * 64;
    int cur = rn[rbeg];
    float run = 0.0f;
#pragma unroll 1
    for (int r = rbeg; r < rbeg + 64; r += 4){
      ushort4v v4 = *(const ushort4v*)&EsT[c*132 + r];
#pragma unroll
      for (int q2 = 0; q2 < 4; ++q2){
        int nd = rn[r + q2];
        if (nd != cur){ atomicAdd(&sums[(size_t)cur*256 + c], run); run = 0.0f; cur = nd; }
        run += bf2f(v4[q2]);
      }
    }
    atomicAdd(&sums[(size_t)cur*256 + c], run);
  }
}

// ---------------- node MLP1 with fused yA construction ----------------
__global__ __launch_bounds__(512)
void gemm_node1(const UST* __restrict__ h, const float* __restrict__ sums,
                const int* __restrict__ offs, const UST* __restrict__ B,
                const float* __restrict__ bias, UST* __restrict__ out){
  __shared__ __attribute__((aligned(16))) UST As0[128*32];
  __shared__ __attribute__((aligned(16))) UST As1[128*32];
  __shared__ __attribute__((aligned(16))) UST Bs0[256*32];
  __shared__ __attribute__((aligned(16))) UST Bs1[256*32];
  int t = threadIdx.x;
  int bM = blockIdx.x;
  int rA = t >> 2, cA = (t & 3) * 8;
  int row = bM*128 + rA;
  bool valid = row < N_NODES;
  float inv = 0.0f;
  if (valid){
    int deg = offs[row+1] - offs[row];
    inv = 1.0f / fmaxf((float)deg, 1.0f);
  }
  const UST* hrow = h + (size_t)row*256;
  const float* srow = sums + (size_t)row*256;
  size_t bb0 = (size_t)rA*512 + cA;
  size_t bb1 = bb0 + (size_t)128*512;
  int lane = t & 63, lm = lane & 15, quad = lane >> 4;
  int wave = t >> 6, wM = (wave >> 2)*64, wN = (wave & 3)*64;
  floatx4 acc[4][4] = {};
  UST* a0d = &As0[rA*32 + cA];
  UST* a1d = &As1[rA*32 + cA];
  UST* b0d0 = &Bs0[rA*32 + cA];
  UST* b0d1 = &Bs0[(128+rA)*32 + cA];
  UST* b1d0 = &Bs1[rA*32 + cA];
  UST* b1d1 = &Bs1[(128+rA)*32 + cA];
  const ushort8v z8 = {0,0,0,0,0,0,0,0};
#pragma unroll 1
  for (int w = 0; w < 8; ++w){
    int k0 = w*64;
    if (k0 < 256){                      // h half via async copy
      if (valid){
        gll16(hrow + k0 + cA,      a0d);
        gll16(hrow + k0 + 32 + cA, a1d);
      } else {
        *(ushort8v*)a0d = z8;
        *(ushort8v*)a1d = z8;
      }
    } else {                            // agg half built from sums/deg
      ushort8v o0 = z8, o1 = z8;
      if (valid){
        int q = k0 - 256 + cA;
        float4 s0 = *(const float4*)(srow + q);
        float4 s1 = *(const float4*)(srow + q + 4);
        o0[0]=f2bf(s0.x*inv); o0[1]=f2bf(s0.y*inv); o0[2]=f2bf(s0.z*inv); o0[3]=f2bf(s0.w*inv);
        o0[4]=f2bf(s1.x*inv); o0[5]=f2bf(s1.y*inv); o0[6]=f2bf(s1.z*inv); o0[7]=f2bf(s1.w*inv);
        float4 s2 = *(const float4*)(srow + q + 32);
        float4 s3 = *(const float4*)(srow + q + 36);
        o1[0]=f2bf(s2.x*inv); o1[1]=f2bf(s2.y*inv); o1[2]=f2bf(s2.z*inv); o1[3]=f2bf(s2.w*inv);
        o1[4]=f2bf(s3.x*inv); o1[5]=f2bf(s3.y*inv); o1[6]=f2bf(s3.z*inv); o1[7]=f2bf(s3.w*inv);
      }
      *(ushort8v*)a0d = o0;
      *(ushort8v*)a1d = o1;
    }
    gll16(B + bb0 + k0,      b0d0);
    gll16(B + bb1 + k0,      b0d1);
    gll16(B + bb0 + k0 + 32, b1d0);
    gll16(B + bb1 + k0 + 32, b1d1);
    __syncthreads();
    mfma_step(As0, Bs0, acc, lm, quad, wM, wN);
    mfma_step(As1, Bs1, acc, lm, quad, wM, wN);
    __syncthreads();
  }
  int mbase = bM*128 + wM + quad*4;
  int nbase = wN + lm;
#pragma unroll
  for (int mi = 0; mi < 4; ++mi)
#pragma unroll
    for (int r = 0; r < 4; ++r){
      int m = mbase + mi*16 + r;
#pragma unroll
      for (int ni = 0; ni < 4; ++ni){
        int n = nbase + ni*16;
        out[(size_t)m*256 + n] = f2bf(siluf(acc[mi][ni][r] + bias[n]));
      }
    }
}

// ---------------- node MLP2: K=256, silu + residual, fp32 out ----------------
__global__ __launch_bounds__(512)
void gemm_node2(const UST* __restrict__ A, const UST* __restrict__ B,
                const float* __restrict__ bias,
                float* __restrict__ out_f, const float* __restrict__ resid){
  __shared__ __attribute__((aligned(16))) UST As0[128*32];
  __shared__ __attribute__((aligned(16))) UST As1[128*32];
  __shared__ __attribute__((aligned(16))) UST Bs0[256*32];
  __shared__ __attribute__((aligned(16))) UST Bs1[256*32];
  int t = threadIdx.x;
  int bM = blockIdx.x;
  int rA = t >> 2, cA = (t & 3) * 8;
  size_t ab  = (size_t)(bM*128 + rA)*256 + cA;
  size_t bb0 = (size_t)rA*256 + cA;
  size_t bb1 = bb0 + (size_t)128*256;
  int lane = t & 63, lm = lane & 15, quad = lane >> 4;
  int wave = t >> 6, wM = (wave >> 2)*64, wN = (wave & 3)*64;
  floatx4 acc[4][4] = {};
  UST* a0d = &As0[rA*32 + cA];
  UST* a1d = &As1[rA*32 + cA];
  UST* b0d0 = &Bs0[rA*32 + cA];
  UST* b0d1 = &Bs0[(128+rA)*32 + cA];
  UST* b1d0 = &Bs1[rA*32 + cA];
  UST* b1d1 = &Bs1[(128+rA)*32 + cA];
#pragma unroll 1
  for (int k0 = 0; k0 < 256; k0 += 64){
    gll16(A + ab + k0,       a0d);
    gll16(A + ab + k0 + 32,  a1d);
    gll16(B + bb0 + k0,      b0d0);
    gll16(B + bb1 + k0,      b0d1);
    gll16(B + bb0 + k0 + 32, b1d0);
    gll16(B + bb1 + k0 + 32, b1d1);
    __syncthreads();
    mfma_step(As0, Bs0, acc, lm, quad, wM, wN);
    mfma_step(As1, Bs1, acc, lm, quad, wM, wN);
    __syncthreads();
  }
  int mbase = bM*128 + wM + quad*4;
  int nbase = wN + lm;
#pragma unroll
  for (int mi = 0; mi < 4; ++mi)
#pragma unroll
    for (int r = 0; r < 4; ++r){
      int m = mbase + mi*16 + r;
      if (m < N_NODES){
#pragma unroll
        for (int ni = 0; ni < 4; ++ni){
          int n = nbase + ni*16;
          float v = siluf(acc[mi][ni][r] + bias[n]);
          out_f[(size_t)m*256 + n] = resid[(size_t)m*256 + n] + v;
        }
      }
    }
}

extern "C" void kernel_launch(void* const* d_in, const int* in_sizes, int n_in,
                              void* d_out, int out_size, void* d_ws, size_t ws_size,
                              hipStream_t stream){
  (void)in_sizes; (void)n_in; (void)out_size; (void)ws_size;
  const float* node_features = (const float*)d_in[0];
  const float* lattices      = (const float*)d_in[1];
  const int*   edge_index    = (const int*)d_in[2];   // [2,E]: row0=src, row1=dst
  const int*   edge2graph    = (const int*)d_in[3];
  const float* frac_diff     = (const float*)d_in[4];
  const float* ln_gamma      = (const float*)d_in[6];
  const float* ln_beta       = (const float*)d_in[7];
  const float* We1 = (const float*)d_in[8];
  const float* be1 = (const float*)d_in[9];
  const float* We2 = (const float*)d_in[10];
  const float* be2 = (const float*)d_in[11];
  const float* Wn1 = (const float*)d_in[12];
  const float* bn1 = (const float*)d_in[13];
  const float* Wn2 = (const float*)d_in[14];
  const float* bn2 = (const float*)d_in[15];

  char* w = (char*)d_ws;
  size_t off_b = 0;
  auto carve = [&](size_t bytes) -> char* {
    char* p = w + off_b; off_b += (bytes + 1023) & ~(size_t)1023; return p;
  };
  UST*   W1T  = (UST*)carve((size_t)256*KE*2);
  U8*    W2f8 = (U8*)carve((size_t)256*256);
  UST*   Wn1T = (UST*)carve((size_t)256*512*2);
  UST*   Wn2T = (UST*)carve((size_t)256*256*2);
  UST*   hbf  = (UST*)carve((size_t)N_NODES*256*2);
  float* ltl  = (float*)carve((size_t)9000*4);
  int*   cnti = (int*)carve((size_t)20480*4);          // padded for int4 scan
  int*   offs = (int*)carve((size_t)(N_NODES+1)*4);
  int*   head = (int*)carve((size_t)N_NODES*4);
  int*   eidx = (int*)carve((size_t)E_EDGES*4);
  int*   srcs = (int*)carve((size_t)E_EDGES*4);        // sorted src per CSR slot
  float* sums = (float*)carve((size_t)N_NODES*256*4);
  U8*    e1f8 = (U8*)carve((size_t)E_EDGES*256);       // fp8 scratch (L2-hot readback)
  UST*   t1   = (UST*)carve((size_t)M_PAD*256*2);

  hipMemsetAsync(cnti, 0, (size_t)20480*4, stream);
  hipMemsetAsync(sums, 0, (size_t)N_NODES*256*4, stream);

  prep_all<<<6732, 256, 0, stream>>>(We1, We2, Wn1, Wn2, node_features,
      ln_gamma, ln_beta, lattices, W1T, W2f8, Wn1T, Wn2T, hbf, ltl);

  cnt_kernel<<<E_EDGES/256, 256, 0, stream>>>(edge_index, cnti);
  scan_kernel<<<1, 256, 0, stream>>>(cnti, offs, head);
  fill_kernel<<<E_EDGES/256, 256, 0, stream>>>(edge_index, head, eidx, srcs);

  gemm_edge_fused<<<E_EDGES/128, 512, 0, stream>>>(
      hbf, edge_index, edge2graph, frac_diff, ltl, W1T, be1, eidx,
      W2f8, be2, srcs, e1f8, sums);

  gemm_node1<<<M_PAD/128, 512, 0, stream>>>(hbf, sums, offs, Wn1T, bn1, t1);

  gemm_node2<<<M_PAD/128, 512, 0, stream>>>(
      t1, Wn2T, bn2, (float*)d_out, node_features);
}

// Round 7
// 495.203 us; speedup vs baseline: 1.0897x; 1.0897x over previous
//
#include <hip/hip_runtime.h>

typedef unsigned short UST;
typedef __bf16 bf16x8 __attribute__((ext_vector_type(8)));
typedef float floatx4 __attribute__((ext_vector_type(4)));
typedef unsigned short ushort8v __attribute__((ext_vector_type(8)));
typedef unsigned short ushort4v __attribute__((ext_vector_type(4)));

#define N_NODES 20000
#define E_EDGES 320000
#define KE 928         // padded edge-MLP K: [hi 0:256 | hj 256:512 | fd(interleaved sin/cos) 512:896 | le 896:905 | pad:928]
#define M_PAD 20096    // 157*128

static __device__ __forceinline__ UST f2bf(float x){
  unsigned int u = __float_as_uint(x);
  u += 0x7fffu + ((u >> 16) & 1u);   // round-to-nearest-even
  return (UST)(u >> 16);
}
static __device__ __forceinline__ float bf2f(UST u){
  return __uint_as_float(((unsigned int)u) << 16);
}
static __device__ __forceinline__ float siluf(float v){
  return v / (1.0f + __expf(-v));
}
// async global->LDS, 16B per lane; LDS dest must be wave-uniform base + lane*16
static __device__ __forceinline__ void gll16(const void* g, void* lds){
  __builtin_amdgcn_global_load_lds(
      (const __attribute__((address_space(1))) unsigned int*)g,
      (__attribute__((address_space(3))) unsigned int*)lds, 16, 0, 0);
}

// As: 128 rows x 32 cols (64B stride). Bs: 256 rows x 32 cols. Wave: 64x64 at (wM,wN).
static __device__ __forceinline__ void mfma_step(const UST* As, const UST* Bs,
    floatx4 (&acc)[4][4], int lm, int quad, int wM, int wN){
  bf16x8 a[4], b[4];
#pragma unroll
  for (int i = 0; i < 4; ++i)
    a[i] = *(const bf16x8*)(As + (wM + i*16 + lm)*32 + quad*8);
#pragma unroll
  for (int i = 0; i < 4; ++i)
    b[i] = *(const bf16x8*)(Bs + (wN + i*16 + lm)*32 + quad*8);
#pragma unroll
  for (int mi = 0; mi < 4; ++mi)
#pragma unroll
    for (int ni = 0; ni < 4; ++ni)
      acc[mi][ni] = __builtin_amdgcn_mfma_f32_16x16x32_bf16(a[mi], b[ni], acc[mi][ni], 0, 0, 0);
}

// second-stage GEMM: A from padded LDS tile [128][264], B direct from global [256][Kb]
static __device__ __forceinline__ void mfma_stage2(const UST* At, const UST* Bg,
    int Kb, floatx4 (&acc)[4][4], int lm, int quad, int wM, int wN){
#pragma unroll 2
  for (int k0 = 0; k0 < 256; k0 += 32){
    bf16x8 a[4], b[4];
#pragma unroll
    for (int i = 0; i < 4; ++i)
      a[i] = *(const bf16x8*)(At + (wM + i*16 + lm)*264 + k0 + quad*8);
#pragma unroll
    for (int i = 0; i < 4; ++i)
      b[i] = *(const bf16x8*)(Bg + (size_t)(wN + i*16 + lm)*Kb + k0 + quad*8);
#pragma unroll
    for (int mi = 0; mi < 4; ++mi)
#pragma unroll
      for (int ni = 0; ni < 4; ++ni)
        acc[mi][ni] = __builtin_amdgcn_mfma_f32_16x16x32_bf16(a[mi], b[ni], acc[mi][ni], 0, 0, 0);
  }
}

// ---------------- fused prep: weights + LayerNorm + ltl + edge histogram ----------------
// W1T row map: [0:512)=hi|hj, [512:896)=fd interleaved (col 512+2j+b -> orig 521+b*192+j),
// [896:905)=le (orig 512..520), [905:928)=0
__global__ __launch_bounds__(256) void prep_all(
    const float* __restrict__ We1, const float* __restrict__ We2,
    const float* __restrict__ Wn1, const float* __restrict__ Wn2,
    const float* __restrict__ x, const float* __restrict__ gamma,
    const float* __restrict__ beta, const float* __restrict__ lat,
    const int* __restrict__ esrc, int* __restrict__ cnti,
    UST* __restrict__ W1T, UST* __restrict__ W2T,
    UST* __restrict__ Wn1T, UST* __restrict__ Wn2T,
    UST* __restrict__ h, float* __restrict__ ltl){
  int bid = blockIdx.x, t = threadIdx.x;
  if (bid < 928){                                   // W1T
    int i = bid*256 + t;
    int n = i / KE, k = i % KE;
    float v = 0.0f;
    if (k < 512)      v = We1[(size_t)k*256 + n];
    else if (k < 896){
      int idx = k - 512, j = idx >> 1, b = idx & 1;
      v = We1[(size_t)(521 + b*192 + j)*256 + n];
    }
    else if (k < 905) v = We1[(size_t)(k-384)*256 + n];
    W1T[i] = f2bf(v);
  } else if (bid < 1184){                           // W2T + Wn2T
    int i = (bid-928)*256 + t;
    int n = i >> 8, k = i & 255;
    W2T[i]  = f2bf(We2[(size_t)k*256 + n]);
    Wn2T[i] = f2bf(Wn2[(size_t)k*256 + n]);
  } else if (bid < 1696){                           // Wn1T
    int i = (bid-1184)*256 + t;
    int n = i >> 9, k = i & 511;
    Wn1T[i] = f2bf(Wn1[(size_t)k*256 + n]);
  } else if (bid < 6696){                           // LayerNorm, 4 rows/block
    int wave = t >> 6, lane = t & 63;
    int row = (bid-1696)*4 + wave;
    const float4* xp = (const float4*)(x + (size_t)row * 256);
    float4 v = xp[lane];
    float s  = v.x + v.y + v.z + v.w;
    float sq = v.x*v.x + v.y*v.y + v.z*v.z + v.w*v.w;
#pragma unroll
    for (int o = 32; o > 0; o >>= 1){ s += __shfl_xor(s, o); sq += __shfl_xor(sq, o); }
    float mu  = s * (1.0f/256.0f);
    float var = sq * (1.0f/256.0f) - mu*mu;
    float rs  = rsqrtf(var + 1e-5f);
    float4 g = ((const float4*)gamma)[lane];
    float4 b = ((const float4*)beta)[lane];
    ushort4v o4;
    o4[0] = f2bf((v.x-mu)*rs*g.x + b.x);
    o4[1] = f2bf((v.y-mu)*rs*g.y + b.y);
    o4[2] = f2bf((v.z-mu)*rs*g.z + b.z);
    o4[3] = f2bf((v.w-mu)*rs*g.w + b.w);
    *(ushort4v*)(h + (size_t)row*256 + lane*4) = o4;
  } else if (bid < 6732){                           // ltl = L @ L^T
    int i = (bid-6696)*256 + t;
    if (i < 9000){
      int g = i / 9, ij = i % 9, a = ij / 3, b = ij % 3;
      const float* L = lat + g*9;
      ltl[i] = L[a*3+0]*L[b*3+0] + L[a*3+1]*L[b*3+1] + L[a*3+2]*L[b*3+2];
    }
  } else {                                          // edge src histogram
    int e = (bid-6732)*256 + t;
    if (e < E_EDGES) atomicAdd(&cnti[esrc[e]], 1);
  }
}

// ---------------- CSR build: scan -> fill (+sorted srcs) ----------------
__global__ __launch_bounds__(256) void scan_kernel(const int* __restrict__ cnti,
    int* __restrict__ off, int* __restrict__ head){
  __shared__ int ps[256];
  int t = threadIdx.x;
  const int CH = 80;                       // 256*80 = 20480 >= 20000 (cnti padded)
  const int4* cp = (const int4*)cnti;
  int base = t * CH;
  int s = 0;
#pragma unroll 1
  for (int i = 0; i < CH/4; ++i){
    int4 v = cp[t*(CH/4) + i];
    int idx = base + i*4;
    if (idx   < N_NODES) s += v.x;
    if (idx+1 < N_NODES) s += v.y;
    if (idx+2 < N_NODES) s += v.z;
    if (idx+3 < N_NODES) s += v.w;
  }
  ps[t] = s; __syncthreads();
#pragma unroll 1
  for (int o = 1; o < 256; o <<= 1){
    int v = (t >= o) ? ps[t - o] : 0;
    __syncthreads();
    ps[t] += v;
    __syncthreads();
  }
  int run = (t > 0) ? ps[t-1] : 0;
#pragma unroll 1
  for (int i = 0; i < CH/4; ++i){
    int4 v = cp[t*(CH/4) + i];
    int idx = base + i*4;
    int a4[4] = {v.x, v.y, v.z, v.w};
#pragma unroll
    for (int j = 0; j < 4; ++j){
      int id = idx + j;
      if (id < N_NODES){ off[id] = run; head[id] = run; run += a4[j]; }
    }
  }
  if (t == 255) off[N_NODES] = run;
}

__global__ __launch_bounds__(256) void fill_kernel(const int* __restrict__ src,
    int* __restrict__ head, int* __restrict__ eidx, int* __restrict__ srcs){
  int e = blockIdx.x*256 + threadIdx.x;
  if (e < E_EDGES){
    int s = src[e];
    int p = atomicAdd(&head[s], 1);
    eidx[p] = e;
    srcs[p] = s;
  }
}

// ======== MEGA-KERNEL: edge MLP1 + MLP2 (LDS-resident tile) + segmented scatter ========
// Phase 1: e1-tile = silu(x @ We1 + be1) -> LDS e1t[128][264] (padded, 2-way-free banks).
// Phase 2: e2 = e1t @ W2T, A-frags from LDS, B-frags direct global (L2-resident W2T),
//          NO barriers in the K-loop.
// Phase 3: silu -> EsT col-major LDS -> 2-half segmented col sums -> atomicAdd sums.
__global__ __launch_bounds__(512, 4)
void gemm_edge_fused(const UST* __restrict__ h, const int* __restrict__ ei,
                     const int* __restrict__ e2g, const float* __restrict__ fdif,
                     const float* __restrict__ ltl, const UST* __restrict__ W1T,
                     const float* __restrict__ be1, const int* __restrict__ eidx,
                     const UST* __restrict__ W2T, const float* __restrict__ be2,
                     const int* __restrict__ rownode, float* __restrict__ sums){
  __shared__ __attribute__((aligned(16))) UST lds[128*264];  // 67.6KB union
  __shared__ int rn[128];
  UST* As0 = lds;             // ph1 staging: 128*32 bf16
  UST* As1 = lds + 4096;
  UST* Bs0 = lds + 8192;      // ph1 staging: 256*32 bf16
  UST* Bs1 = lds + 16384;
  UST* e1t = lds;             // ph2: [128 rows][264 cols pad]
  UST* EsT = lds;             // ph3: [256 cols][132 rows pad]
  int t = threadIdx.x;
  int bM = blockIdx.x;
  int rA = t >> 2, cA = (t & 3) * 8;       // one A-row per thread, 8-ushort chunk
  int p0 = bM*128 + rA;
  int e0 = eidx[p0];
  int src0 = ei[e0];
  int dst0 = ei[E_EDGES + e0];
  int g0 = e2g[e0];
  float f0x = fdif[e0*3+0], f0y = fdif[e0*3+1], f0z = fdif[e0*3+2];
  size_t btb0 = (size_t)rA*KE + cA;        // W1T rows rA, rA+128
  size_t btb1 = btb0 + (size_t)128*KE;
  int lane = t & 63, lm = lane & 15, quad = lane >> 4;
  int wave = t >> 6, wM = (wave >> 2)*64, wN = (wave & 3)*64;
  floatx4 acc[4][4] = {};
  UST* a0d = &As0[rA*32 + cA];
  UST* a1d = &As1[rA*32 + cA];
  UST* b0d0 = &Bs0[rA*32 + cA];
  UST* b0d1 = &Bs0[(128+rA)*32 + cA];
  UST* b1d0 = &Bs1[rA*32 + cA];
  UST* b1d1 = &Bs1[(128+rA)*32 + cA];
  if (t < 128) rn[t] = rownode[bM*128 + t];

  // ---- phase 1: K-loop over KE ----
#pragma unroll 1
  for (int w = 0; w < 8; ++w){            // hi (w<4) then hj (w>=4)
    int k0 = w*64;
    const UST* srow = (w < 4) ? (h + (size_t)src0*256 + k0)
                              : (h + (size_t)dst0*256 + (k0 - 256));
    gll16(srow + cA,      a0d);
    gll16(srow + 32 + cA, a1d);
    gll16(W1T + btb0 + k0,      b0d0);
    gll16(W1T + btb1 + k0,      b0d1);
    gll16(W1T + btb0 + k0 + 32, b1d0);
    gll16(W1T + btb1 + k0 + 32, b1d1);
    __syncthreads();
    mfma_step(As0, Bs0, acc, lm, quad, wM, wN);
    mfma_step(As1, Bs1, acc, lm, quad, wM, wN);
    __syncthreads();
  }
#pragma unroll 1
  for (int w = 8; w < 14; ++w){           // fd: interleaved sin/cos pairs
    int k0 = w*64;
    gll16(W1T + btb0 + k0,      b0d0);    // issue DMA before the VALU burst
    gll16(W1T + btb1 + k0,      b0d1);
    gll16(W1T + btb0 + k0 + 32, b1d0);
    gll16(W1T + btb1 + k0 + 32, b1d1);
    int jb0 = (k0 + cA - 512) >> 1;       // 4 angles per half-window
    ushort8v o0, o1;
#pragma unroll
    for (int ii = 0; ii < 4; ++ii){
      int jj = jb0 + ii;
      int dim = jj >> 6; float kf = (float)(jj & 63);
      float fr = (dim == 0) ? f0x : ((dim == 1) ? f0y : f0z);
      float q = __builtin_amdgcn_fractf(fr * kf);
      o0[2*ii]   = f2bf(__builtin_amdgcn_sinf(q));
      o0[2*ii+1] = f2bf(__builtin_amdgcn_cosf(q));
    }
#pragma unroll
    for (int ii = 0; ii < 4; ++ii){
      int jj = jb0 + 16 + ii;
      int dim = jj >> 6; float kf = (float)(jj & 63);
      float fr = (dim == 0) ? f0x : ((dim == 1) ? f0y : f0z);
      float q = __builtin_amdgcn_fractf(fr * kf);
      o1[2*ii]   = f2bf(__builtin_amdgcn_sinf(q));
      o1[2*ii+1] = f2bf(__builtin_amdgcn_cosf(q));
    }
    *(ushort8v*)a0d = o0;
    *(ushort8v*)a1d = o1;
    __syncthreads();
    mfma_step(As0, Bs0, acc, lm, quad, wM, wN);
    mfma_step(As1, Bs1, acc, lm, quad, wM, wN);
    __syncthreads();
  }
  {                                       // half window k0=896: le + pad (As0/Bs0 only)
    gll16(W1T + btb0 + 896, b0d0);
    gll16(W1T + btb1 + 896, b0d1);
    ushort8v o0;
#pragma unroll
    for (int i = 0; i < 8; ++i){
      int c = cA + i;
      o0[i] = (c < 9) ? f2bf(ltl[g0*9 + c]) : (UST)0;
    }
    *(ushort8v*)a0d = o0;
    __syncthreads();
    mfma_step(As0, Bs0, acc, lm, quad, wM, wN);
  }
  __syncthreads();   // staging reads done; union becomes e1t
  // phase-1 epilogue: silu -> bf16 into LDS e1t (C-layout scatter, ~4-way b16 writes)
#pragma unroll
  for (int mi = 0; mi < 4; ++mi)
#pragma unroll
    for (int r = 0; r < 4; ++r){
      int ml = wM + mi*16 + quad*4 + r;
#pragma unroll
      for (int ni = 0; ni < 4; ++ni){
        int nl = wN + ni*16 + lm;
        float v = acc[mi][ni][r] + be1[nl];
        e1t[ml*264 + nl] = f2bf(siluf(v));
      }
    }
  __syncthreads();

  // ---- phase 2: barrier-free K-loop, A from e1t, B from global W2T ----
  floatx4 acc2[4][4] = {};
  mfma_stage2(e1t, W2T, 256, acc2, lm, quad, wM, wN);
  __syncthreads();   // e1t reads done; union becomes EsT

  // ---- phase 3: silu + transpose-store to EsT, 2-half segmented col sums ----
#pragma unroll
  for (int mi = 0; mi < 4; ++mi)
#pragma unroll
    for (int ni = 0; ni < 4; ++ni){
      int nl = wN + ni*16 + lm;
      int ml = wM + mi*16 + quad*4;
      ushort4v pk;
#pragma unroll
      for (int r = 0; r < 4; ++r)
        pk[r] = f2bf(siluf(acc2[mi][ni][r] + be2[nl]));
      *(ushort4v*)&EsT[nl*132 + ml] = pk;
    }
  __syncthreads();
  {
    int c = t & 255, hh = t >> 8;        // all 512 threads: (col, row-half)
    int rbeg = hh * 64;
    int cur = rn[rbeg];
    float run = 0.0f;
#pragma unroll 1
    for (int r = rbeg; r < rbeg + 64; r += 4){
      ushort4v v4 = *(const ushort4v*)&EsT[c*132 + r];
#pragma unroll
      for (int q2 = 0; q2 < 4; ++q2){
        int nd = rn[r + q2];
        if (nd != cur){ atomicAdd(&sums[(size_t)cur*256 + c], run); run = 0.0f; cur = nd; }
        run += bf2f(v4[q2]);
      }
    }
    atomicAdd(&sums[(size_t)cur*256 + c], run);
  }
}

// ======== fused node MLP1 + MLP2 (same LDS-resident-tile trick) ========
// Phase 1: y1-tile = silu([h|agg] @ Wn1 + bn1) -> LDS y1t[128][264].
// Phase 2: A from y1t, B direct global Wn2T; silu + resid -> fp32 out (m < N_NODES).
__global__ __launch_bounds__(512, 4)
void gemm_node12(const UST* __restrict__ h, const float* __restrict__ sums,
                 const int* __restrict__ offs, const UST* __restrict__ B1,
                 const float* __restrict__ bn1, const UST* __restrict__ B2,
                 const float* __restrict__ bn2,
                 float* __restrict__ out_f, const float* __restrict__ resid){
  __shared__ __attribute__((aligned(16))) UST lds[128*264];
  UST* As0 = lds;
  UST* As1 = lds + 4096;
  UST* Bs0 = lds + 8192;
  UST* Bs1 = lds + 16384;
  UST* y1t = lds;
  int t = threadIdx.x;
  int bM = blockIdx.x;
  int rA = t >> 2, cA = (t & 3) * 8;
  int row = bM*128 + rA;
  bool valid = row < N_NODES;
  float inv = 0.0f;
  if (valid){
    int deg = offs[row+1] - offs[row];
    inv = 1.0f / fmaxf((float)deg, 1.0f);
  }
  const UST* hrow = h + (size_t)row*256;
  const float* srow = sums + (size_t)row*256;
  size_t bb0 = (size_t)rA*512 + cA;
  size_t bb1 = bb0 + (size_t)128*512;
  int lane = t & 63, lm = lane & 15, quad = lane >> 4;
  int wave = t >> 6, wM = (wave >> 2)*64, wN = (wave & 3)*64;
  floatx4 acc[4][4] = {};
  UST* a0d = &As0[rA*32 + cA];
  UST* a1d = &As1[rA*32 + cA];
  UST* b0d0 = &Bs0[rA*32 + cA];
  UST* b0d1 = &Bs0[(128+rA)*32 + cA];
  UST* b1d0 = &Bs1[rA*32 + cA];
  UST* b1d1 = &Bs1[(128+rA)*32 + cA];
  const ushort8v z8 = {0,0,0,0,0,0,0,0};
#pragma unroll 1
  for (int w = 0; w < 8; ++w){
    int k0 = w*64;
    if (k0 < 256){                      // h half via async copy
      if (valid){
        gll16(hrow + k0 + cA,      a0d);
        gll16(hrow + k0 + 32 + cA, a1d);
      } else {
        *(ushort8v*)a0d = z8;
        *(ushort8v*)a1d = z8;
      }
    } else {                            // agg half built from sums/deg
      ushort8v o0 = z8, o1 = z8;
      if (valid){
        int q = k0 - 256 + cA;
        float4 s0 = *(const float4*)(srow + q);
        float4 s1 = *(const float4*)(srow + q + 4);
        o0[0]=f2bf(s0.x*inv); o0[1]=f2bf(s0.y*inv); o0[2]=f2bf(s0.z*inv); o0[3]=f2bf(s0.w*inv);
        o0[4]=f2bf(s1.x*inv); o0[5]=f2bf(s1.y*inv); o0[6]=f2bf(s1.z*inv); o0[7]=f2bf(s1.w*inv);
        float4 s2 = *(const float4*)(srow + q + 32);
        float4 s3 = *(const float4*)(srow + q + 36);
        o1[0]=f2bf(s2.x*inv); o1[1]=f2bf(s2.y*inv); o1[2]=f2bf(s2.z*inv); o1[3]=f2bf(s2.w*inv);
        o1[4]=f2bf(s3.x*inv); o1[5]=f2bf(s3.y*inv); o1[6]=f2bf(s3.z*inv); o1[7]=f2bf(s3.w*inv);
      }
      *(ushort8v*)a0d = o0;
      *(ushort8v*)a1d = o1;
    }
    gll16(B1 + bb0 + k0,      b0d0);
    gll16(B1 + bb1 + k0,      b0d1);
    gll16(B1 + bb0 + k0 + 32, b1d0);
    gll16(B1 + bb1 + k0 + 32, b1d1);
    __syncthreads();
    mfma_step(As0, Bs0, acc, lm, quad, wM, wN);
    mfma_step(As1, Bs1, acc, lm, quad, wM, wN);
    __syncthreads();
  }
  __syncthreads();
  // epilogue 1: silu -> y1t
#pragma unroll
  for (int mi = 0; mi < 4; ++mi)
#pragma unroll
    for (int r = 0; r < 4; ++r){
      int ml = wM + mi*16 + quad*4 + r;
#pragma unroll
      for (int ni = 0; ni < 4; ++ni){
        int nl = wN + ni*16 + lm;
        y1t[ml*264 + nl] = f2bf(siluf(acc[mi][ni][r] + bn1[nl]));
      }
    }
  __syncthreads();
  // phase 2: barrier-free
  floatx4 acc2[4][4] = {};
  mfma_stage2(y1t, B2, 256, acc2, lm, quad, wM, wN);
  int mbase = bM*128 + wM + quad*4;
  int nbase = wN + lm;
#pragma unroll
  for (int mi = 0; mi < 4; ++mi)
#pragma unroll
    for (int r = 0; r < 4; ++r){
      int m = mbase + mi*16 + r;
      if (m < N_NODES){
#pragma unroll
        for (int ni = 0; ni < 4; ++ni){
          int n = nbase + ni*16;
          float v = siluf(acc2[mi][ni][r] + bn2[n]);
          out_f[(size_t)m*256 + n] = resid[(size_t)m*256 + n] + v;
        }
      }
    }
}

extern "C" void kernel_launch(void* const* d_in, const int* in_sizes, int n_in,
                              void* d_out, int out_size, void* d_ws, size_t ws_size,
                              hipStream_t stream){
  (void)in_sizes; (void)n_in; (void)out_size; (void)ws_size;
  const float* node_features = (const float*)d_in[0];
  const float* lattices      = (const float*)d_in[1];
  const int*   edge_index    = (const int*)d_in[2];   // [2,E]: row0=src, row1=dst
  const int*   edge2graph    = (const int*)d_in[3];
  const float* frac_diff     = (const float*)d_in[4];
  const float* ln_gamma      = (const float*)d_in[6];
  const float* ln_beta       = (const float*)d_in[7];
  const float* We1 = (const float*)d_in[8];
  const float* be1 = (const float*)d_in[9];
  const float* We2 = (const float*)d_in[10];
  const float* be2 = (const float*)d_in[11];
  const float* Wn1 = (const float*)d_in[12];
  const float* bn1 = (const float*)d_in[13];
  const float* Wn2 = (const float*)d_in[14];
  const float* bn2 = (const float*)d_in[15];

  char* w = (char*)d_ws;
  size_t off_b = 0;
  auto carve = [&](size_t bytes) -> char* {
    char* p = w + off_b; off_b += (bytes + 1023) & ~(size_t)1023; return p;
  };
  UST*   W1T  = (UST*)carve((size_t)256*KE*2);
  UST*   W2T  = (UST*)carve((size_t)256*256*2);
  UST*   Wn1T = (UST*)carve((size_t)256*512*2);
  UST*   Wn2T = (UST*)carve((size_t)256*256*2);
  UST*   hbf  = (UST*)carve((size_t)N_NODES*256*2);
  float* ltl  = (float*)carve((size_t)9000*4);
  int*   cnti = (int*)carve((size_t)20480*4);          // padded for int4 scan
  int*   offs = (int*)carve((size_t)(N_NODES+1)*4);
  int*   head = (int*)carve((size_t)N_NODES*4);
  int*   eidx = (int*)carve((size_t)E_EDGES*4);
  int*   srcs = (int*)carve((size_t)E_EDGES*4);        // sorted src per CSR slot
  float* sums = (float*)carve((size_t)N_NODES*256*4);

  hipMemsetAsync(cnti, 0, (size_t)20480*4, stream);
  hipMemsetAsync(sums, 0, (size_t)N_NODES*256*4, stream);

  prep_all<<<6732 + E_EDGES/256, 256, 0, stream>>>(We1, We2, Wn1, Wn2,
      node_features, ln_gamma, ln_beta, lattices, edge_index, cnti,
      W1T, W2T, Wn1T, Wn2T, hbf, ltl);

  scan_kernel<<<1, 256, 0, stream>>>(cnti, offs, head);
  fill_kernel<<<E_EDGES/256, 256, 0, stream>>>(edge_index, head, eidx, srcs);

  gemm_edge_fused<<<E_EDGES/128, 512, 0, stream>>>(
      hbf, edge_index, edge2graph, frac_diff, ltl, W1T, be1, eidx,
      W2T, be2, srcs, sums);

  gemm_node12<<<M_PAD/128, 512, 0, stream>>>(
      hbf, sums, offs, Wn1T, bn1, Wn2T, bn2, (float*)d_out, node_features);
}